// Round 2
// baseline (88.644 us; speedup 1.0000x reference)
//
#include <hip/hip_runtime.h>
#include <math.h>

#define NP 8192
#define SEQ 4
#define KNN 16
#define R2 1.0f
#define SCALE (1.0f / (float)(SEQ * NP * KNN))

// One wave (64 lanes) per query point; block = 256 threads = 4 waves.
// Phase 1: scan candidates 256/iteration in ascending index order with a
// one-window register prefetch pipeline (the early-exit break otherwise
// serializes each iteration on full load latency). Hits are extracted from
// ballot masks in ascending-bit order (matches reference scan order).
// Phase 2: lane = k + 16*s computes one (seq,k) distance term; wave reduce;
// per-block partial -> one fp32 atomicAdd into d_out (zeroed by memsetAsync).
__global__ __launch_bounds__(256) void ballq_fused(
    const float* __restrict__ xyz,   // [NP,3]
    const float* __restrict__ pf,    // [SEQ,NP,3]
    float* __restrict__ out)         // [1], pre-zeroed
{
    const int lane = threadIdx.x & 63;
    const int wv   = threadIdx.x >> 6;
    const int i    = (blockIdx.x << 2) + wv;   // query point

    const float xi = xyz[3 * i + 0];
    const float yi = xyz[3 * i + 1];
    const float zi = xyz[3 * i + 2];

    int myNbr = -1;   // neighbor index owned by lane c (c-th hit)
    int cnt   = 0;    // wave-uniform hit count
    int first = -1;   // wave-uniform first hit (for padding)

    // Prefetch window 0 (candidates 0..255, 4 per lane).
    float cx[4], cy[4], cz[4];
#pragma unroll
    for (int u = 0; u < 4; ++u) {
        const int j = (u << 6) + lane;
        cx[u] = xyz[3 * j + 0];
        cy[u] = xyz[3 * j + 1];
        cz[u] = xyz[3 * j + 2];
    }

    for (int base = 0; base < NP; base += 256) {
        // Prefetch window k+1 (wrapped; values unused past the break / end).
        float nx[4], ny[4], nz[4];
#pragma unroll
        for (int u = 0; u < 4; ++u) {
            const int j = (base + 256 + (u << 6) + lane) & (NP - 1);
            nx[u] = xyz[3 * j + 0];
            ny[u] = xyz[3 * j + 1];
            nz[u] = xyz[3 * j + 2];
        }

        unsigned long long masks[4];
#pragma unroll
        for (int u = 0; u < 4; ++u) {
            const float dx = cx[u] - xi;
            const float dy = cy[u] - yi;
            const float dz = cz[u] - zi;
            masks[u] = __ballot(dx * dx + dy * dy + dz * dz < R2);
        }

#pragma unroll
        for (int u = 0; u < 4; ++u) {
            unsigned long long m = masks[u];
            const int sub = base + (u << 6);
            while (m && cnt < KNN) {              // wave-uniform loop
                const int b = __builtin_ctzll(m);
                const int j = sub + b;
                if (cnt == 0) first = j;
                if (lane == cnt) myNbr = j;       // lane c takes hit c
                ++cnt;
                m &= m - 1;
            }
        }
        if (cnt >= KNN) break;                    // wave-uniform early exit

#pragma unroll
        for (int u = 0; u < 4; ++u) { cx[u] = nx[u]; cy[u] = ny[u]; cz[u] = nz[u]; }
    }
    if (myNbr < 0) myNbr = first;                 // pad lanes [cnt,16) with first hit

    // Phase 2: lane = k + 16*s -> one (seq s, neighbor k) distance term.
    const int k = lane & 15;
    const int s = lane >> 4;
    const int j = __shfl(myNbr, k);
    const size_t oi = ((size_t)s * NP + i) * 3;
    const size_t oj = ((size_t)s * NP + j) * 3;
    const float dx = pf[oi + 0] - pf[oj + 0];
    const float dy = pf[oi + 1] - pf[oj + 1];
    const float dz = pf[oi + 2] - pf[oj + 2];
    float d = sqrtf(fmaxf(dx * dx + dy * dy + dz * dz, 1e-24f));

    // 64-lane butterfly reduction
#pragma unroll
    for (int off = 32; off > 0; off >>= 1) d += __shfl_xor(d, off);

    __shared__ float sacc[4];
    if (lane == 0) sacc[wv] = d;
    __syncthreads();
    if (threadIdx.x == 0)
        atomicAdd(out, (sacc[0] + sacc[1] + sacc[2] + sacc[3]) * SCALE);
}

extern "C" void kernel_launch(void* const* d_in, const int* in_sizes, int n_in,
                              void* d_out, int out_size, void* d_ws, size_t ws_size,
                              hipStream_t stream) {
    const float* xyz = (const float*)d_in[0];  // pc_source [1,8192,3]
    const float* pf  = (const float*)d_in[1];  // pred_flow [4,8192,3]
    float* out       = (float*)d_out;

    hipMemsetAsync(out, 0, sizeof(float), stream);   // d_out is poisoned 0xAA
    ballq_fused<<<NP / 4, 256, 0, stream>>>(xyz, pf, out);
}